// Round 1
// baseline (404.113 us; speedup 1.0000x reference)
//
#include <hip/hip_runtime.h>
#include <hip/hip_bf16.h>

// ModuleCorrelation: 9x9 cost volume (MD=4), B=4 C=64 H=192 W=320, fp32.
// out[b, dy*9+dx, y, x] = (1/64) sum_c first[b,c,y,x] * second_pad[b,c,y+dy-4,x+dx-4]
//
// Design: output-stationary. Thread owns TX=2 x-pixels, all 81 accumulators.
// Block (32,8) covers a 64x8 pixel tile. `second` staged in LDS
// (16 rows x 72 cols per channel, CH_STAGE=4 channels per barrier pair).
// Window rows read as 5x ds_read_b64 (even-aligned), 18 FMA per row.
// `first` read directly from global as float2 (coalesced).

#define MDV      4
#define NDISP    81
#define TILE_X   64
#define TILE_Y   8
#define CH_STAGE 4
#define LDS_ROWS (TILE_Y + 2 * MDV)   // 16
#define LDS_COLS (TILE_X + 2 * MDV)   // 72

__global__ __launch_bounds__(256, 2)
void corr_kernel(const float* __restrict__ first,
                 const float* __restrict__ second,
                 float* __restrict__ out) {
    const int C = 64, H = 192, W = 320;
    const int HW = H * W;

    __shared__ float lds[CH_STAGE][LDS_ROWS * LDS_COLS];

    const int tx = threadIdx.x;          // 0..31
    const int ty = threadIdx.y;          // 0..7
    const int tid = ty * 32 + tx;        // 0..255
    const int x_tile = blockIdx.x * TILE_X;
    const int y_tile = blockIdx.y * TILE_Y;
    const int b = blockIdx.z;

    const int x0 = x_tile + 2 * tx;      // first of the 2 x-pixels this thread owns
    const int y  = y_tile + ty;          // output row

    const float* fst_b = first  + (size_t)b * C * HW;
    const float* sec_b = second + (size_t)b * C * HW;

    float acc[NDISP][2];
#pragma unroll
    for (int d = 0; d < NDISP; ++d) { acc[d][0] = 0.f; acc[d][1] = 0.f; }

    for (int cb = 0; cb < C; cb += CH_STAGE) {
        __syncthreads();  // protect LDS reuse from previous stage
        // ---- fill LDS: CH_STAGE channels, rows [y_tile-4, y_tile+11], cols [x_tile-4, x_tile+67]
        const int total = CH_STAGE * LDS_ROWS * LDS_COLS;  // 4608
#pragma unroll
        for (int k = 0; k < total / 256; ++k) {
            int i = tid + k * 256;
            int c   = i / (LDS_ROWS * LDS_COLS);
            int rem = i - c * (LDS_ROWS * LDS_COLS);
            int r   = rem / LDS_COLS;
            int col = rem - r * LDS_COLS;
            int gy = y_tile - MDV + r;
            int gx = x_tile - MDV + col;
            float v = 0.f;
            if ((unsigned)gy < (unsigned)H && (unsigned)gx < (unsigned)W)
                v = sec_b[(size_t)(cb + c) * HW + gy * W + gx];
            lds[c][rem] = v;
        }
        __syncthreads();

        // ---- compute over the staged channels
#pragma unroll
        for (int cl = 0; cl < CH_STAGE; ++cl) {
            const int c = cb + cl;
            const float2 f = *(const float2*)&fst_b[(size_t)c * HW + y * W + x0];
#pragma unroll
            for (int r = 0; r < 9; ++r) {
                const float* row = &lds[cl][(ty + r) * LDS_COLS + 2 * tx];
                float w[10];
#pragma unroll
                for (int k = 0; k < 5; ++k) {
                    float2 t2 = *(const float2*)&row[2 * k];
                    w[2 * k] = t2.x; w[2 * k + 1] = t2.y;
                }
#pragma unroll
                for (int dx = 0; dx < 9; ++dx) {
                    acc[r * 9 + dx][0] += f.x * w[dx];
                    acc[r * 9 + dx][1] += f.y * w[dx + 1];
                }
            }
        }
    }

    // ---- epilogue: scale by 1/64, coalesced float2 stores
    const float scale = 1.0f / 64.0f;
    float* out_b = out + (size_t)b * NDISP * HW;
#pragma unroll
    for (int d = 0; d < NDISP; ++d) {
        float2 o;
        o.x = acc[d][0] * scale;
        o.y = acc[d][1] * scale;
        *(float2*)&out_b[(size_t)d * HW + y * W + x0] = o;
    }
}

extern "C" void kernel_launch(void* const* d_in, const int* in_sizes, int n_in,
                              void* d_out, int out_size, void* d_ws, size_t ws_size,
                              hipStream_t stream) {
    const float* tenFirst  = (const float*)d_in[0];
    const float* tenSecond = (const float*)d_in[1];
    float* out = (float*)d_out;

    dim3 block(32, 8, 1);
    dim3 grid(320 / TILE_X, 192 / TILE_Y, 4);  // (5, 24, 4) = 480 blocks
    corr_kernel<<<grid, block, 0, stream>>>(tenFirst, tenSecond, out);
}

// Round 2
// 252.942 us; speedup vs baseline: 1.5977x; 1.5977x over previous
//
#include <hip/hip_runtime.h>
#include <hip/hip_bf16.h>

// ModuleCorrelation as implicit GEMM on MFMA (bf16 in, fp32 acc).
// out[b, dy*9+dx, y, x] = (1/64) sum_c F[b,c,y,x] * S[b,c,y+dy-4,x+dx-4]
//
// Pipeline (all on `stream`):
//   1. fill_zero:  zero the padded channels-last S buffer in d_ws
//   2. conv_pad:   S fp32 [C][H][W] -> bf16 [H+8][W+8][C] (LDS transpose, +4 offset)
//   3. corr_mfma:  per wave: one (b, y, 16-px x-tile). G[m,n] = sum_c A[m,c]*B[c,n]
//      with n in [0,24) the x'-window; band-extract out[dx,m] = G[m,m+dx].
//      A from F fp32 directly (coalesced dword + cvt); B as per-lane contiguous
//      dwordx4 from channels-last S_p. Epilogue: LDS transpose -> coalesced stores.

#define WW   320
#define HH   192
#define CC   64
#define HWSZ (HH * WW)
#define NB   4
#define PW   328   // WW + 8
#define PH   200   // HH + 8
#define NDISP 81

typedef __attribute__((ext_vector_type(8))) short bf16x8_t;   // 8 bf16 (4 VGPRs)
typedef __attribute__((ext_vector_type(4))) float f32x4_t;    // 4 fp32

static __device__ __forceinline__ unsigned short f2bf(float f) {
    unsigned int u = __float_as_uint(f);
    u += 0x7fffu + ((u >> 16) & 1u);   // round-nearest-even
    return (unsigned short)(u >> 16);
}

// ---------------- kernel 1: zero the padded S_p buffer ----------------
__global__ __launch_bounds__(256) void fill_zero(uint4* __restrict__ p, int n4) {
    int i = blockIdx.x * 256 + threadIdx.x;
    if (i < n4) {
        uint4 z; z.x = 0u; z.y = 0u; z.z = 0u; z.w = 0u;
        p[i] = z;
    }
}

// ---------------- kernel 2: S fp32 CHW -> bf16 (H+8)(W+8)C, +4 offset ----------------
__global__ __launch_bounds__(256) void conv_pad(const float* __restrict__ S,
                                                unsigned short* __restrict__ Sp) {
    __shared__ float tile[64][65];   // [c][x], +1 pad
    const int tx = threadIdx.x;      // 0..63 (x)
    const int ty = threadIdx.y;      // 0..3  (c-chunk)
    const int x0 = blockIdx.x * 64;
    const int y  = blockIdx.y;
    const int b  = blockIdx.z;

    const float* src = S + (size_t)b * CC * HWSZ + (size_t)y * WW + x0 + tx;
#pragma unroll
    for (int i = 0; i < 16; ++i) {
        int c = ty * 16 + i;
        tile[c][tx] = src[(size_t)c * HWSZ];   // coalesced 64 dwords per wave-quarter
    }
    __syncthreads();

    const int t  = ty * 64 + tx;     // 0..255
    const int xx = t >> 2;           // 0..63
    const int cg = (t & 3) * 16;     // 0,16,32,48
    unsigned short tmp[16];
#pragma unroll
    for (int i = 0; i < 16; ++i) tmp[i] = f2bf(tile[cg + i][xx]);  // 2-way bank alias: free

    unsigned short* dst = Sp + (((size_t)b * PH + (y + 4)) * PW + (x0 + xx + 4)) * CC + cg;
    uint4 v;
    v.x = (unsigned)tmp[0]  | ((unsigned)tmp[1]  << 16);
    v.y = (unsigned)tmp[2]  | ((unsigned)tmp[3]  << 16);
    v.z = (unsigned)tmp[4]  | ((unsigned)tmp[5]  << 16);
    v.w = (unsigned)tmp[6]  | ((unsigned)tmp[7]  << 16);
    *(uint4*)dst = v;
    v.x = (unsigned)tmp[8]  | ((unsigned)tmp[9]  << 16);
    v.y = (unsigned)tmp[10] | ((unsigned)tmp[11] << 16);
    v.z = (unsigned)tmp[12] | ((unsigned)tmp[13] << 16);
    v.w = (unsigned)tmp[14] | ((unsigned)tmp[15] << 16);
    *(uint4*)(dst + 8) = v;
}

// ---------------- kernel 3: the MFMA correlation ----------------
__global__ __launch_bounds__(256) void corr_mfma(const float* __restrict__ F,
                                                 const unsigned short* __restrict__ Sp,
                                                 float* __restrict__ out) {
    __shared__ float lds[4][NDISP * 16];   // per-wave [d][m] staging, 20.7 KB

    const int tid  = threadIdx.x;
    const int wave = tid >> 6;
    const int lane = tid & 63;
    const int q    = lane >> 4;     // quad 0..3
    const int col  = lane & 15;

    const int wid = blockIdx.x * 4 + wave;      // 0..15359
    const int xt  = wid % 20;
    const int y   = (wid / 20) % HH;
    const int b   = wid / (20 * HH);
    const int x0  = xt * 16;

    // ---- A fragments: A[m=col][k=8q+j (+32)] = F[b][k][y][x0+m], coalesced per quad
    bf16x8_t a0, a1;
    const float* fb = F + (size_t)b * CC * HWSZ + (size_t)y * WW + x0 + col;
#pragma unroll
    for (int j = 0; j < 8; ++j) {
        a0[j] = (short)f2bf(fb[(size_t)(q * 8 + j) * HWSZ]);
        a1[j] = (short)f2bf(fb[(size_t)(32 + q * 8 + j) * HWSZ]);
    }

    f32x4_t acc[9][2];
#pragma unroll
    for (int i = 0; i < 9; ++i)
#pragma unroll
        for (int nt = 0; nt < 2; ++nt)
#pragma unroll
            for (int r = 0; r < 4; ++r) acc[i][nt][r] = 0.f;

    // ---- K-loop over dy: B[k=8q+j(+32)][n=col+16nt] = S_p[b][y+dy][x0+n][k]
#pragma unroll
    for (int dyi = 0; dyi < 9; ++dyi) {
        const unsigned short* srow = Sp + ((size_t)b * PH + (y + dyi)) * PW * CC;
#pragma unroll
        for (int nt = 0; nt < 2; ++nt) {
            int xp = x0 + col + 16 * nt;            // padded x' index
            xp = xp > (PW - 1) ? (PW - 1) : xp;     // clamp: n>=24 never used in band
            const unsigned short* p = srow + (size_t)xp * CC + q * 8;
            bf16x8_t b0 = *(const bf16x8_t*)(p);        // k = 0..31 slice  (16 B aligned)
            bf16x8_t b1 = *(const bf16x8_t*)(p + 32);   // k = 32..63 slice
            acc[dyi][nt] = __builtin_amdgcn_mfma_f32_16x16x32_bf16(a0, b0, acc[dyi][nt], 0, 0, 0);
            acc[dyi][nt] = __builtin_amdgcn_mfma_f32_16x16x32_bf16(a1, b1, acc[dyi][nt], 0, 0, 0);
        }
    }

    // ---- epilogue: band-extract C-layout (row m = 4q+r, col n) into [d][m] LDS
    float* my = lds[wave];
    const float scale = 1.0f / 64.0f;
#pragma unroll
    for (int dyi = 0; dyi < 9; ++dyi)
#pragma unroll
        for (int nt = 0; nt < 2; ++nt)
#pragma unroll
            for (int r = 0; r < 4; ++r) {
                int m  = 4 * q + r;
                int dx = col + 16 * nt - m;         // n - m
                if (dx >= 0 && dx <= 8)
                    my[(dyi * 9 + dx) * 16 + m] = acc[dyi][nt][r] * scale;
            }
    __syncthreads();   // orders per-wave LDS RAW (cross-lane); uniform control flow

    // ---- coalesced stores: 64 lanes = 4 d-planes x 16 consecutive x
    float* ob = out + (size_t)b * NDISP * HWSZ + (size_t)y * WW + x0;
#pragma unroll
    for (int rnd = 0; rnd < 21; ++rnd) {
        int idx = rnd * 64 + lane;
        if (rnd < 20 || idx < NDISP * 16) {
            int d = idx >> 4, m = idx & 15;
            ob[(size_t)d * HWSZ + m] = my[idx];
        }
    }
}

// ---------------- fallback (round-1 direct kernel) if ws too small ----------------
#define MDV      4
#define TILE_X   64
#define TILE_Y   8
#define CH_STAGE 4
#define LDS_ROWS (TILE_Y + 2 * MDV)
#define LDS_COLS (TILE_X + 2 * MDV)

__global__ __launch_bounds__(256, 2)
void corr_direct(const float* __restrict__ first,
                 const float* __restrict__ second,
                 float* __restrict__ out) {
    const int C = 64, H = HH, W = WW;
    const int HW = H * W;
    __shared__ float lds[CH_STAGE][LDS_ROWS * LDS_COLS];
    const int tx = threadIdx.x, ty = threadIdx.y;
    const int tid = ty * 32 + tx;
    const int x_tile = blockIdx.x * TILE_X;
    const int y_tile = blockIdx.y * TILE_Y;
    const int b = blockIdx.z;
    const int x0 = x_tile + 2 * tx;
    const int y  = y_tile + ty;
    const float* fst_b = first  + (size_t)b * C * HW;
    const float* sec_b = second + (size_t)b * C * HW;
    float acc[NDISP][2];
#pragma unroll
    for (int d = 0; d < NDISP; ++d) { acc[d][0] = 0.f; acc[d][1] = 0.f; }
    for (int cb = 0; cb < C; cb += CH_STAGE) {
        __syncthreads();
        const int total = CH_STAGE * LDS_ROWS * LDS_COLS;
#pragma unroll
        for (int k = 0; k < total / 256; ++k) {
            int i = tid + k * 256;
            int c   = i / (LDS_ROWS * LDS_COLS);
            int rem = i - c * (LDS_ROWS * LDS_COLS);
            int r   = rem / LDS_COLS;
            int cl  = rem - r * LDS_COLS;
            int gy = y_tile - MDV + r;
            int gx = x_tile - MDV + cl;
            float v = 0.f;
            if ((unsigned)gy < (unsigned)H && (unsigned)gx < (unsigned)W)
                v = sec_b[(size_t)(cb + c) * HW + gy * W + gx];
            lds[c][rem] = v;
        }
        __syncthreads();
#pragma unroll
        for (int cl = 0; cl < CH_STAGE; ++cl) {
            const int c = cb + cl;
            const float2 f = *(const float2*)&fst_b[(size_t)c * HW + y * W + x0];
#pragma unroll
            for (int r = 0; r < 9; ++r) {
                const float* row = &lds[cl][(ty + r) * LDS_COLS + 2 * tx];
                float w[10];
#pragma unroll
                for (int k = 0; k < 5; ++k) {
                    float2 t2 = *(const float2*)&row[2 * k];
                    w[2 * k] = t2.x; w[2 * k + 1] = t2.y;
                }
#pragma unroll
                for (int dx = 0; dx < 9; ++dx) {
                    acc[r * 9 + dx][0] += f.x * w[dx];
                    acc[r * 9 + dx][1] += f.y * w[dx + 1];
                }
            }
        }
    }
    const float scale = 1.0f / 64.0f;
    float* out_b = out + (size_t)b * NDISP * HW;
#pragma unroll
    for (int d = 0; d < NDISP; ++d) {
        float2 o;
        o.x = acc[d][0] * scale;
        o.y = acc[d][1] * scale;
        *(float2*)&out_b[(size_t)d * HW + y * W + x0] = o;
    }
}

extern "C" void kernel_launch(void* const* d_in, const int* in_sizes, int n_in,
                              void* d_out, int out_size, void* d_ws, size_t ws_size,
                              hipStream_t stream) {
    const float* tenFirst  = (const float*)d_in[0];
    const float* tenSecond = (const float*)d_in[1];
    float* out = (float*)d_out;

    const size_t sp_bytes = (size_t)NB * PH * PW * CC * 2;   // 33.6 MB bf16 padded S

    if (ws_size >= sp_bytes) {
        unsigned short* Sp = (unsigned short*)d_ws;
        const int n4 = (int)(sp_bytes / 16);                 // 2,099,200 uint4
        fill_zero<<<(n4 + 255) / 256, 256, 0, stream>>>((uint4*)d_ws, n4);
        conv_pad<<<dim3(WW / 64, HH, NB), dim3(64, 4), 0, stream>>>(tenSecond, Sp);
        const int nblocks = NB * HH * (WW / 16) / 4;         // 3840
        corr_mfma<<<nblocks, 256, 0, stream>>>(tenFirst, Sp, out);
    } else {
        corr_direct<<<dim3(WW / TILE_X, HH / TILE_Y, NB), dim3(32, 8), 0, stream>>>(
            tenFirst, tenSecond, out);
    }
}

// Round 3
// 252.530 us; speedup vs baseline: 1.6003x; 1.0016x over previous
//
#include <hip/hip_runtime.h>
#include <hip/hip_bf16.h>

// ModuleCorrelation as implicit GEMM on MFMA (bf16 in, fp32 acc), v3.
// out[b, dy*9+dx, y, x] = (1/64) sum_c F[b,c,y,x] * S[b,c,y+dy-4,x+dx-4]
//
// Pipeline:
//   1. fill_zero:   zero padded channels-last S buffer (Sp)
//   2. conv_first:  F fp32 [C][H][W] -> bf16 [H][W][C]           (Fc)
//   3. conv_pad:    S fp32 [C][H][W] -> bf16 [H+8][W+8][C] (+4)  (Sp)
//   4. corr_mfma_v3: wave owns (b, y-pair, 16-px x-tile). YB=2 shares 8/9 of
//      the B rows between the two y's (40 b128 B-loads feed 72 MFMAs).
//      XCD slab swizzle: blockIdx%8 -> fixed 24-row y-slab for L2 locality.
//      Epilogue: per-wave LDS band-extract (stride-18 pad), no barrier.

#define WW   320
#define HH   192
#define CC   64
#define HWSZ (HH * WW)
#define NB   4
#define PW   328   // WW + 8
#define PH   200   // HH + 8
#define NDISP 81
#define EST  18    // epilogue LDS stride (16 + 2 pad: kills bank conflicts)

typedef __attribute__((ext_vector_type(8))) short bf16x8_t;   // 8 bf16 (4 VGPRs)
typedef __attribute__((ext_vector_type(4))) float f32x4_t;    // 4 fp32

static __device__ __forceinline__ unsigned short f2bf(float f) {
    unsigned int u = __float_as_uint(f);
    u += 0x7fffu + ((u >> 16) & 1u);   // round-nearest-even
    return (unsigned short)(u >> 16);
}

// ---------------- kernel 1: zero the padded S_p buffer ----------------
__global__ __launch_bounds__(256) void fill_zero(uint4* __restrict__ p, int n4) {
    int i = blockIdx.x * 256 + threadIdx.x;
    if (i < n4) {
        uint4 z; z.x = 0u; z.y = 0u; z.z = 0u; z.w = 0u;
        p[i] = z;
    }
}

// ---------------- kernel 2: F fp32 CHW -> bf16 HWC (no pad) ----------------
__global__ __launch_bounds__(256) void conv_first(const float* __restrict__ F,
                                                  unsigned short* __restrict__ Fc) {
    __shared__ float tile[64][65];
    const int tx = threadIdx.x;      // 0..63 (x)
    const int ty = threadIdx.y;      // 0..3  (c-chunk)
    const int x0 = blockIdx.x * 64;
    const int y  = blockIdx.y;
    const int b  = blockIdx.z;

    const float* src = F + (size_t)b * CC * HWSZ + (size_t)y * WW + x0 + tx;
#pragma unroll
    for (int i = 0; i < 16; ++i) {
        int c = ty * 16 + i;
        tile[c][tx] = src[(size_t)c * HWSZ];
    }
    __syncthreads();

    const int t  = ty * 64 + tx;
    const int xx = t >> 2;
    const int cg = (t & 3) * 16;
    unsigned short tmp[16];
#pragma unroll
    for (int i = 0; i < 16; ++i) tmp[i] = f2bf(tile[cg + i][xx]);

    unsigned short* dst = Fc + (((size_t)b * HH + y) * WW + (x0 + xx)) * CC + cg;
    uint4 v;
    v.x = (unsigned)tmp[0]  | ((unsigned)tmp[1]  << 16);
    v.y = (unsigned)tmp[2]  | ((unsigned)tmp[3]  << 16);
    v.z = (unsigned)tmp[4]  | ((unsigned)tmp[5]  << 16);
    v.w = (unsigned)tmp[6]  | ((unsigned)tmp[7]  << 16);
    *(uint4*)dst = v;
    v.x = (unsigned)tmp[8]  | ((unsigned)tmp[9]  << 16);
    v.y = (unsigned)tmp[10] | ((unsigned)tmp[11] << 16);
    v.z = (unsigned)tmp[12] | ((unsigned)tmp[13] << 16);
    v.w = (unsigned)tmp[14] | ((unsigned)tmp[15] << 16);
    *(uint4*)(dst + 8) = v;
}

// ---------------- kernel 3: S fp32 CHW -> bf16 (H+8)(W+8)C, +4 offset ----------------
__global__ __launch_bounds__(256) void conv_pad(const float* __restrict__ S,
                                                unsigned short* __restrict__ Sp) {
    __shared__ float tile[64][65];
    const int tx = threadIdx.x;
    const int ty = threadIdx.y;
    const int x0 = blockIdx.x * 64;
    const int y  = blockIdx.y;
    const int b  = blockIdx.z;

    const float* src = S + (size_t)b * CC * HWSZ + (size_t)y * WW + x0 + tx;
#pragma unroll
    for (int i = 0; i < 16; ++i) {
        int c = ty * 16 + i;
        tile[c][tx] = src[(size_t)c * HWSZ];
    }
    __syncthreads();

    const int t  = ty * 64 + tx;
    const int xx = t >> 2;
    const int cg = (t & 3) * 16;
    unsigned short tmp[16];
#pragma unroll
    for (int i = 0; i < 16; ++i) tmp[i] = f2bf(tile[cg + i][xx]);

    unsigned short* dst = Sp + (((size_t)b * PH + (y + 4)) * PW + (x0 + xx + 4)) * CC + cg;
    uint4 v;
    v.x = (unsigned)tmp[0]  | ((unsigned)tmp[1]  << 16);
    v.y = (unsigned)tmp[2]  | ((unsigned)tmp[3]  << 16);
    v.z = (unsigned)tmp[4]  | ((unsigned)tmp[5]  << 16);
    v.w = (unsigned)tmp[6]  | ((unsigned)tmp[7]  << 16);
    *(uint4*)dst = v;
    v.x = (unsigned)tmp[8]  | ((unsigned)tmp[9]  << 16);
    v.y = (unsigned)tmp[10] | ((unsigned)tmp[11] << 16);
    v.z = (unsigned)tmp[12] | ((unsigned)tmp[13] << 16);
    v.w = (unsigned)tmp[14] | ((unsigned)tmp[15] << 16);
    *(uint4*)(dst + 8) = v;
}

// ---------------- kernel 4: MFMA correlation, YB=2 + XCD slab swizzle ----------------
__global__ __launch_bounds__(256)
void corr_mfma_v3(const unsigned short* __restrict__ Fc,
                  const unsigned short* __restrict__ Sp,
                  float* __restrict__ out) {
    __shared__ float ebuf[4][NDISP * EST];   // per-wave epilogue staging, 23.3 KB

    const int tid  = threadIdx.x;
    const int wave = tid >> 6;
    const int lane = tid & 63;
    const int q    = lane >> 4;
    const int col  = lane & 15;

    // ---- XCD slab decode: blockIdx%8 (heuristic XCD id) -> fixed 24-row y-slab
    const int i    = blockIdx.x;          // 0..1919
    const int xcd  = i & 7;
    const int j    = i >> 3;              // 0..239
    const int b    = j / 60;
    const int r60  = j % 60;
    const int pql  = r60 / 20;            // 0..2
    const int xt   = r60 % 20;
    const int pq   = xcd * 3 + pql;       // 0..23
    const int yp   = pq * 4 + wave;       // ypair 0..95
    const int y0   = yp * 2;
    const int x0   = xt * 16;

    // ---- A fragments for both y rows: per-lane contiguous b128 from Fc
    const unsigned short* fc =
        Fc + (((size_t)b * HH + y0) * WW + (x0 + col)) * CC + q * 8;
    const bf16x8_t a00 = *(const bf16x8_t*)(fc);                 // y0, k 0..31
    const bf16x8_t a01 = *(const bf16x8_t*)(fc + 32);            // y0, k 32..63
    const bf16x8_t a10 = *(const bf16x8_t*)(fc + (size_t)WW * CC);      // y0+1
    const bf16x8_t a11 = *(const bf16x8_t*)(fc + (size_t)WW * CC + 32);

    f32x4_t acc[2][9][2];
#pragma unroll
    for (int p = 0; p < 2; ++p)
#pragma unroll
        for (int d = 0; d < 9; ++d)
#pragma unroll
            for (int nt = 0; nt < 2; ++nt)
#pragma unroll
                for (int k = 0; k < 4; ++k) acc[p][d][nt][k] = 0.f;

    // ---- shared B rows: padded rows y0 .. y0+9 feed both y-parts
#pragma unroll
    for (int rr = 0; rr < 10; ++rr) {
        const unsigned short* srow = Sp + ((size_t)b * PH + (y0 + rr)) * PW * CC;
#pragma unroll
        for (int nt = 0; nt < 2; ++nt) {
            int xp = x0 + col + 16 * nt;
            xp = xp > (PW - 1) ? (PW - 1) : xp;   // clamped lanes never enter the band
            const unsigned short* p = srow + (size_t)xp * CC + q * 8;
            const bf16x8_t b0 = *(const bf16x8_t*)(p);
            const bf16x8_t b1 = *(const bf16x8_t*)(p + 32);
            if (rr < 9) {
                acc[0][rr][nt] = __builtin_amdgcn_mfma_f32_16x16x32_bf16(a00, b0, acc[0][rr][nt], 0, 0, 0);
                acc[0][rr][nt] = __builtin_amdgcn_mfma_f32_16x16x32_bf16(a01, b1, acc[0][rr][nt], 0, 0, 0);
            }
            if (rr >= 1) {
                acc[1][rr - 1][nt] = __builtin_amdgcn_mfma_f32_16x16x32_bf16(a10, b0, acc[1][rr - 1][nt], 0, 0, 0);
                acc[1][rr - 1][nt] = __builtin_amdgcn_mfma_f32_16x16x32_bf16(a11, b1, acc[1][rr - 1][nt], 0, 0, 0);
            }
        }
    }

    // ---- epilogue per y-part: band-extract -> per-wave LDS (stride 18) -> stores
    const float scale = 1.0f / 64.0f;
    float* my = ebuf[wave];
#pragma unroll
    for (int p = 0; p < 2; ++p) {
#pragma unroll
        for (int dyi = 0; dyi < 9; ++dyi)
#pragma unroll
            for (int nt = 0; nt < 2; ++nt)
#pragma unroll
                for (int k = 0; k < 4; ++k) {
                    int m  = 4 * q + k;
                    int dx = col + 16 * nt - m;
                    if (dx >= 0 && dx <= 8)
                        my[(dyi * 9 + dx) * EST + m] = acc[p][dyi][nt][k] * scale;
                }
        // in-wave lgkmcnt ordering: no barrier needed for per-wave staging
        float* ob = out + (size_t)b * NDISP * HWSZ + (size_t)(y0 + p) * WW + x0;
#pragma unroll
        for (int rnd = 0; rnd < 21; ++rnd) {
            int idx = rnd * 64 + lane;
            if (rnd < 20 || idx < NDISP * 16) {
                int d = idx >> 4, m = idx & 15;
                ob[(size_t)d * HWSZ + m] = my[d * EST + m];
            }
        }
    }
}

// ---------------- mid fallback: round-2 MFMA kernel (F fp32 direct) ----------------
__global__ __launch_bounds__(256) void corr_mfma(const float* __restrict__ F,
                                                 const unsigned short* __restrict__ Sp,
                                                 float* __restrict__ out) {
    __shared__ float lds[4][NDISP * 16];
    const int tid  = threadIdx.x;
    const int wave = tid >> 6;
    const int lane = tid & 63;
    const int q    = lane >> 4;
    const int col  = lane & 15;
    const int wid = blockIdx.x * 4 + wave;
    const int xt  = wid % 20;
    const int y   = (wid / 20) % HH;
    const int b   = wid / (20 * HH);
    const int x0  = xt * 16;

    bf16x8_t a0, a1;
    const float* fb = F + (size_t)b * CC * HWSZ + (size_t)y * WW + x0 + col;
#pragma unroll
    for (int j = 0; j < 8; ++j) {
        a0[j] = (short)f2bf(fb[(size_t)(q * 8 + j) * HWSZ]);
        a1[j] = (short)f2bf(fb[(size_t)(32 + q * 8 + j) * HWSZ]);
    }
    f32x4_t acc[9][2];
#pragma unroll
    for (int i = 0; i < 9; ++i)
#pragma unroll
        for (int nt = 0; nt < 2; ++nt)
#pragma unroll
            for (int r = 0; r < 4; ++r) acc[i][nt][r] = 0.f;
#pragma unroll
    for (int dyi = 0; dyi < 9; ++dyi) {
        const unsigned short* srow = Sp + ((size_t)b * PH + (y + dyi)) * PW * CC;
#pragma unroll
        for (int nt = 0; nt < 2; ++nt) {
            int xp = x0 + col + 16 * nt;
            xp = xp > (PW - 1) ? (PW - 1) : xp;
            const unsigned short* p = srow + (size_t)xp * CC + q * 8;
            bf16x8_t b0 = *(const bf16x8_t*)(p);
            bf16x8_t b1 = *(const bf16x8_t*)(p + 32);
            acc[dyi][nt] = __builtin_amdgcn_mfma_f32_16x16x32_bf16(a0, b0, acc[dyi][nt], 0, 0, 0);
            acc[dyi][nt] = __builtin_amdgcn_mfma_f32_16x16x32_bf16(a1, b1, acc[dyi][nt], 0, 0, 0);
        }
    }
    float* my = lds[wave];
    const float scale = 1.0f / 64.0f;
#pragma unroll
    for (int dyi = 0; dyi < 9; ++dyi)
#pragma unroll
        for (int nt = 0; nt < 2; ++nt)
#pragma unroll
            for (int r = 0; r < 4; ++r) {
                int m  = 4 * q + r;
                int dx = col + 16 * nt - m;
                if (dx >= 0 && dx <= 8)
                    my[(dyi * 9 + dx) * 16 + m] = acc[dyi][nt][r] * scale;
            }
    __syncthreads();
    float* ob = out + (size_t)b * NDISP * HWSZ + (size_t)y * WW + x0;
#pragma unroll
    for (int rnd = 0; rnd < 21; ++rnd) {
        int idx = rnd * 64 + lane;
        if (rnd < 20 || idx < NDISP * 16) {
            int d = idx >> 4, m = idx & 15;
            ob[(size_t)d * HWSZ + m] = my[idx];
        }
    }
}

// ---------------- last-resort fallback: direct fp32 kernel ----------------
#define MDV      4
#define TILE_X   64
#define TILE_Y   8
#define CH_STAGE 4
#define LDS_ROWS (TILE_Y + 2 * MDV)
#define LDS_COLS (TILE_X + 2 * MDV)

__global__ __launch_bounds__(256, 2)
void corr_direct(const float* __restrict__ first,
                 const float* __restrict__ second,
                 float* __restrict__ out) {
    const int C = 64, H = HH, W = WW;
    const int HW = H * W;
    __shared__ float lds[CH_STAGE][LDS_ROWS * LDS_COLS];
    const int tx = threadIdx.x, ty = threadIdx.y;
    const int tid = ty * 32 + tx;
    const int x_tile = blockIdx.x * TILE_X;
    const int y_tile = blockIdx.y * TILE_Y;
    const int b = blockIdx.z;
    const int x0 = x_tile + 2 * tx;
    const int y  = y_tile + ty;
    const float* fst_b = first  + (size_t)b * C * HW;
    const float* sec_b = second + (size_t)b * C * HW;
    float acc[NDISP][2];
#pragma unroll
    for (int d = 0; d < NDISP; ++d) { acc[d][0] = 0.f; acc[d][1] = 0.f; }
    for (int cb = 0; cb < C; cb += CH_STAGE) {
        __syncthreads();
        const int total = CH_STAGE * LDS_ROWS * LDS_COLS;
#pragma unroll
        for (int k = 0; k < total / 256; ++k) {
            int i = tid + k * 256;
            int c   = i / (LDS_ROWS * LDS_COLS);
            int rem = i - c * (LDS_ROWS * LDS_COLS);
            int r   = rem / LDS_COLS;
            int cl  = rem - r * LDS_COLS;
            int gy = y_tile - MDV + r;
            int gx = x_tile - MDV + cl;
            float v = 0.f;
            if ((unsigned)gy < (unsigned)H && (unsigned)gx < (unsigned)W)
                v = sec_b[(size_t)(cb + c) * HW + gy * W + gx];
            lds[c][rem] = v;
        }
        __syncthreads();
#pragma unroll
        for (int cl = 0; cl < CH_STAGE; ++cl) {
            const int c = cb + cl;
            const float2 f = *(const float2*)&fst_b[(size_t)c * HW + y * W + x0];
#pragma unroll
            for (int r = 0; r < 9; ++r) {
                const float* row = &lds[cl][(ty + r) * LDS_COLS + 2 * tx];
                float w[10];
#pragma unroll
                for (int k = 0; k < 5; ++k) {
                    float2 t2 = *(const float2*)&row[2 * k];
                    w[2 * k] = t2.x; w[2 * k + 1] = t2.y;
                }
#pragma unroll
                for (int dx = 0; dx < 9; ++dx) {
                    acc[r * 9 + dx][0] += f.x * w[dx];
                    acc[r * 9 + dx][1] += f.y * w[dx + 1];
                }
            }
        }
    }
    const float scale = 1.0f / 64.0f;
    float* out_b = out + (size_t)b * NDISP * HW;
#pragma unroll
    for (int d = 0; d < NDISP; ++d) {
        float2 o;
        o.x = acc[d][0] * scale;
        o.y = acc[d][1] * scale;
        *(float2*)&out_b[(size_t)d * HW + y * W + x0] = o;
    }
}

extern "C" void kernel_launch(void* const* d_in, const int* in_sizes, int n_in,
                              void* d_out, int out_size, void* d_ws, size_t ws_size,
                              hipStream_t stream) {
    const float* tenFirst  = (const float*)d_in[0];
    const float* tenSecond = (const float*)d_in[1];
    float* out = (float*)d_out;

    const size_t sp_bytes = (size_t)NB * PH * PW * CC * 2;   // 33.6 MB bf16 padded S
    const size_t fc_bytes = (size_t)NB * HH * WW * CC * 2;   // 31.5 MB bf16 F

    if (ws_size >= sp_bytes + fc_bytes) {
        unsigned short* Sp = (unsigned short*)d_ws;
        unsigned short* Fc = (unsigned short*)((char*)d_ws + sp_bytes);
        const int n4 = (int)(sp_bytes / 16);
        fill_zero<<<(n4 + 255) / 256, 256, 0, stream>>>((uint4*)Sp, n4);
        conv_first<<<dim3(WW / 64, HH, NB), dim3(64, 4), 0, stream>>>(tenFirst, Fc);
        conv_pad<<<dim3(WW / 64, HH, NB), dim3(64, 4), 0, stream>>>(tenSecond, Sp);
        corr_mfma_v3<<<1920, 256, 0, stream>>>(Fc, Sp, out);
    } else if (ws_size >= sp_bytes) {
        unsigned short* Sp = (unsigned short*)d_ws;
        const int n4 = (int)(sp_bytes / 16);
        fill_zero<<<(n4 + 255) / 256, 256, 0, stream>>>((uint4*)Sp, n4);
        conv_pad<<<dim3(WW / 64, HH, NB), dim3(64, 4), 0, stream>>>(tenSecond, Sp);
        corr_mfma<<<NB * HH * 20 / 4, 256, 0, stream>>>(tenFirst, Sp, out);
    } else {
        corr_direct<<<dim3(WW / TILE_X, HH / TILE_Y, NB), dim3(32, 8), 0, stream>>>(
            tenFirst, tenSecond, out);
    }
}